// Round 4
// baseline (547.969 us; speedup 1.0000x reference)
//
#include <hip/hip_runtime.h>
#include <math.h>

#define BN 2
#define HH 160
#define WW 160
#define CDATA 8
#define PS 10
#define STR 5
#define N1 31
#define N2 31
#define NSITE (N1*N2)
#define SWIN 15
#define NOFF 225
#define KK 7
#define EDIM 800
#define CHUNK 256
#define NPIX 25600          // HH*WW
#define LP 40               // conv2 LDS pitch (ushorts)
#define KP 480              // agg A k-pitch (= 15 dj * 32 j2-slots)
#define COLP 992            // ypT col pitch (31 j1 * 32 j2-slots)

typedef __attribute__((ext_vector_type(8))) short s8v;
typedef __attribute__((ext_vector_type(8))) unsigned short u8v;
typedef __attribute__((ext_vector_type(4))) float f4v;

__device__ __forceinline__ unsigned short f2bf(float f) {
    unsigned u = __float_as_uint(f);
    return (unsigned short)((u + 0x7FFFu + ((u >> 16) & 1u)) >> 16);
}
__device__ __forceinline__ float bf2f(unsigned short h) {
    return __uint_as_float(((unsigned)h) << 16);
}

// ---------- block reductions ----------
__device__ __forceinline__ float block_sum(float v, float* sred) {
    #pragma unroll
    for (int o = 32; o; o >>= 1) v += __shfl_xor(v, o);
    __syncthreads();
    if ((threadIdx.x & 63) == 0) sred[threadIdx.x >> 6] = v;
    __syncthreads();
    return sred[0] + sred[1] + sred[2] + sred[3];
}
__device__ __forceinline__ float block_max(float v, float* sred) {
    #pragma unroll
    for (int o = 32; o; o >>= 1) v = fmaxf(v, __shfl_xor(v, o));
    __syncthreads();
    if ((threadIdx.x & 63) == 0) sred[threadIdx.x >> 6] = v;
    __syncthreads();
    return fmaxf(fmaxf(sred[0], sred[1]), fmaxf(sred[2], sred[3]));
}

// ---------- prepack conv2 weights: [2][n=64][k=576] ----------
__global__ __launch_bounds__(256) void prepack_w2_k(const float* __restrict__ ew2,
                                                    const float* __restrict__ tw2,
                                                    unsigned short* __restrict__ wp) {
    int idx = blockIdx.x * 256 + threadIdx.x;
    if (idx >= 2 * 64 * 576) return;
    int which = idx / (64 * 576); int r = idx % (64 * 576);
    int n = r / 576, k = r % 576;
    int p = k / 64, c = k % 64;
    const float* w = which ? tw2 : ew2;
    wp[idx] = f2bf(w[(n * 64 + c) * 9 + p]);
}

// ---------- conv1 (e+t fused) -> bf16 NHWC h1 [b][pix][128] ----------
__global__ __launch_bounds__(256) void conv1_k(const float* __restrict__ xf,
                                               const float* __restrict__ ew1,
                                               const float* __restrict__ eb1,
                                               const float* __restrict__ tw1,
                                               const float* __restrict__ tb1,
                                               unsigned short* __restrict__ h1) {
    int x = blockIdx.x * 16 + threadIdx.x;
    int y = blockIdx.y * 16 + threadIdx.y;
    int z = blockIdx.z; int b = z >> 3, g = z & 7;
    const float* wgt  = (g < 4) ? ew1 : tw1;
    const float* bias = (g < 4) ? eb1 : tb1;
    int co0 = (g & 3) * 16;
    float acc[16];
    #pragma unroll
    for (int u = 0; u < 16; u++) acc[u] = bias[co0 + u];
    const float* inb = xf + (size_t)b * 8 * NPIX;
    for (int c = 0; c < 8; ++c) {
        const float* inc = inb + c * NPIX;
        #pragma unroll
        for (int dy = 0; dy < 3; ++dy) {
            int yy = y + dy - 1; bool yok = (yy >= 0 && yy < HH);
            #pragma unroll
            for (int dx = 0; dx < 3; ++dx) {
                int xx = x + dx - 1;
                float v = (yok && xx >= 0 && xx < WW) ? inc[yy * WW + xx] : 0.f;
                #pragma unroll
                for (int u = 0; u < 16; u++)
                    acc[u] = fmaf(v, wgt[((co0 + u) * 8 + c) * 9 + dy * 3 + dx], acc[u]);
            }
        }
    }
    u8v o0, o1;
    #pragma unroll
    for (int u = 0; u < 8; u++) o0[u] = f2bf(fmaxf(acc[u], 0.f));
    #pragma unroll
    for (int u = 0; u < 8; u++) o1[u] = f2bf(fmaxf(acc[8 + u], 0.f));
    unsigned short* dst = h1 + ((size_t)b * NPIX + y * WW + x) * 128 + g * 16;
    *(u8v*)dst = o0;
    *(u8v*)(dst + 8) = o1;
}

// ---------- conv2: bf16 MFMA implicit GEMM ----------
__global__ __launch_bounds__(256) void conv2_mfma_k(const unsigned short* __restrict__ h1,
                                                    const unsigned short* __restrict__ wp,
                                                    const float* __restrict__ eb2,
                                                    const float* __restrict__ tb2,
                                                    unsigned short* __restrict__ h2) {
    __shared__ unsigned short Al[64 * LP];
    __shared__ unsigned short Bl[64 * LP];
    const int t = threadIdx.x;
    const int which = blockIdx.y;
    const int m0 = blockIdx.x * 64;
    const int wv = t >> 6, lane = t & 63;
    const int n0w = (wv >> 1) * 32, m0w = (wv & 1) * 32;
    f4v a00 = {0.f,0.f,0.f,0.f}, a01 = a00, a10 = a00, a11 = a00;
    const unsigned short* wb = wp + (size_t)which * 64 * 576;
    const int sm = t >> 2, sq = (t & 3) * 8;
    const int mp = m0 + sm;
    const int b = mp / NPIX, rp = mp % NPIX;
    const int py = rp / WW, px = rp % WW;
    for (int step = 0; step < 18; ++step) {
        const int p = step >> 1, ch = (step & 1) * 32;
        const int dy = p / 3 - 1, dx = p % 3 - 1;
        s8v av = *(const s8v*)(wb + sm * 576 + p * 64 + ch + sq);
        s8v bv;
        #pragma unroll
        for (int j = 0; j < 8; j++) bv[j] = 0;
        int yy = py + dy, xx = px + dx;
        if (yy >= 0 && yy < HH && xx >= 0 && xx < WW)
            bv = *(const s8v*)((const short*)h1 + ((size_t)b * NPIX + yy * WW + xx) * 128 + which * 64 + ch + sq);
        __syncthreads();
        *(s8v*)((short*)Al + sm * LP + sq) = av;
        *(s8v*)((short*)Bl + sm * LP + sq) = bv;
        __syncthreads();
        s8v af0 = *(const s8v*)((const short*)Al + (n0w      + (lane & 15)) * LP + (lane >> 4) * 8);
        s8v af1 = *(const s8v*)((const short*)Al + (n0w + 16 + (lane & 15)) * LP + (lane >> 4) * 8);
        s8v bf0 = *(const s8v*)((const short*)Bl + (m0w      + (lane & 15)) * LP + (lane >> 4) * 8);
        s8v bf1 = *(const s8v*)((const short*)Bl + (m0w + 16 + (lane & 15)) * LP + (lane >> 4) * 8);
        a00 = __builtin_amdgcn_mfma_f32_16x16x32_bf16(af0, bf0, a00, 0, 0, 0);
        a01 = __builtin_amdgcn_mfma_f32_16x16x32_bf16(af0, bf1, a01, 0, 0, 0);
        a10 = __builtin_amdgcn_mfma_f32_16x16x32_bf16(af1, bf0, a10, 0, 0, 0);
        a11 = __builtin_amdgcn_mfma_f32_16x16x32_bf16(af1, bf1, a11, 0, 0, 0);
    }
    const float* bias = which ? tb2 : eb2;
    #pragma unroll
    for (int fj = 0; fj < 2; ++fj) {
        int nb = n0w + fj * 16 + (lane >> 4) * 4;
        f4v bv4 = *(const f4v*)(bias + nb);
        #pragma unroll
        for (int fi = 0; fi < 2; ++fi) {
            f4v ac = fj ? (fi ? a11 : a10) : (fi ? a01 : a00);
            int mm = m0 + m0w + fi * 16 + (lane & 15);
            ushort4 o;
            o.x = f2bf(fmaxf(ac[0] + bv4[0], 0.f));
            o.y = f2bf(fmaxf(ac[1] + bv4[1], 0.f));
            o.z = f2bf(fmaxf(ac[2] + bv4[2], 0.f));
            o.w = f2bf(fmaxf(ac[3] + bv4[3], 0.f));
            *(ushort4*)(h2 + ((size_t)which * 51200 + mm) * 64 + nb) = o;
        }
    }
}

// ---------- conv3 (e+t fused) ----------
__global__ __launch_bounds__(256) void conv3_k(const unsigned short* __restrict__ h2,
                                               const float* __restrict__ ew3,
                                               const float* __restrict__ eb3,
                                               const float* __restrict__ tw3,
                                               const float* __restrict__ tb3,
                                               float* __restrict__ xe,
                                               float* __restrict__ ltm) {
    int x = blockIdx.x * 16 + threadIdx.x;
    int y = blockIdx.y * 16 + threadIdx.y;
    int z = blockIdx.z; int b = z >> 1, which = z & 1;
    const unsigned short* h2b = h2 + ((size_t)which * 51200 + b * NPIX) * 64;
    if (which == 0) {
        float acc[8];
        #pragma unroll
        for (int u = 0; u < 8; u++) acc[u] = eb3[u];
        #pragma unroll
        for (int pos = 0; pos < 9; ++pos) {
            int yy = y + pos / 3 - 1, xx = x + pos % 3 - 1;
            if (yy < 0 || yy >= HH || xx < 0 || xx >= WW) continue;
            const unsigned short* row = h2b + ((size_t)yy * WW + xx) * 64;
            for (int cq = 0; cq < 8; ++cq) {
                u8v v = *(const u8v*)(row + cq * 8);
                #pragma unroll
                for (int j = 0; j < 8; ++j) {
                    float f = bf2f(v[j]);
                    int c = cq * 8 + j;
                    #pragma unroll
                    for (int u = 0; u < 8; u++)
                        acc[u] = fmaf(f, ew3[(u * 64 + c) * 9 + pos], acc[u]);
                }
            }
        }
        float* dst = xe + ((size_t)b * NPIX + y * WW + x) * 8;
        #pragma unroll
        for (int u = 0; u < 8; u++) dst[u] = acc[u];
    } else {
        float acc = tb3[0];
        #pragma unroll
        for (int pos = 0; pos < 9; ++pos) {
            int yy = y + pos / 3 - 1, xx = x + pos % 3 - 1;
            if (yy < 0 || yy >= HH || xx < 0 || xx >= WW) continue;
            const unsigned short* row = h2b + ((size_t)yy * WW + xx) * 64;
            for (int cq = 0; cq < 8; ++cq) {
                u8v v = *(const u8v*)(row + cq * 8);
                #pragma unroll
                for (int j = 0; j < 8; ++j)
                    acc = fmaf(bf2f(v[j]), tw3[(cq * 8 + j) * 9 + pos], acc);
            }
        }
        ltm[b * NPIX + y * WW + x] = acc;
    }
}

// ---------- im2patch (NHWC xe): ye[site][e] ----------
__global__ __launch_bounds__(256) void im2patch_k(const float* __restrict__ xe,
                                                  const float* __restrict__ ltm,
                                                  float* __restrict__ ye,
                                                  float* __restrict__ yn,
                                                  float* __restrict__ tempv) {
    __shared__ float sred[4];
    int site = blockIdx.x;
    int b = site / NSITE; int ij = site % NSITE;
    int i1 = ij / N2, i2 = ij % N2;
    int t = threadIdx.x;
    const float* xeb = xe + (size_t)b * NPIX * 8;
    float* yrow = ye + (size_t)site * EDIM;
    float ssq = 0.f;
    for (int e = t; e < EDIM; e += 256) {
        int rr = e / 80, rem = e % 80;
        float v = xeb[((size_t)(i1 * STR + rr) * WW + i2 * STR) * 8 + rem];
        yrow[e] = v; ssq += v * v;
    }
    float tot = block_sum(ssq, sred);
    if (t == 0) yn[site] = tot;
    float sl = 0.f;
    if (t < 100) {
        int rr = t / 10, q = t % 10;
        sl = ltm[(size_t)b * NPIX + (i1 * STR + rr) * WW + (i2 * STR + q)];
    }
    float slt = block_sum(sl, sred);
    if (t == 0) tempv[site] = expf(slt * (1.f / 100.f));
}

// ---------- gram: per (b, i1, dj) 31x31 dot block ----------
__global__ __launch_bounds__(128) void gram_k(const float* __restrict__ ye,
                                              float* __restrict__ dots) {
    __shared__ float As[32 * CHUNK];
    __shared__ float Bs[32 * CHUNK];
    int blk = blockIdx.x;
    int b = blk / 465; int r = blk % 465;
    int i1 = r / 15, dj = r % 15;
    int b1 = min(max(i1 - 7, 0), 16);
    int j1 = b1 + dj;
    const float* Arow = ye + (size_t)(b * N1 + i1) * N2 * EDIM;
    const float* Brow = ye + (size_t)(b * N1 + j1) * N2 * EDIM;
    int t = threadIdx.x;
    int tx = t & 15, ty = t >> 4;
    float acc[4][2];
    #pragma unroll
    for (int i = 0; i < 4; i++) { acc[i][0] = 0.f; acc[i][1] = 0.f; }
    for (int kc = 0; kc < EDIM; kc += CHUNK) {
        int len = min(CHUNK, EDIM - kc);
        int nq = len >> 2;
        for (int idx = t; idx < 31 * nq; idx += 128) {
            int row = idx / nq, gq = idx % nq;
            int sw = 4 * (gq ^ (row & 7));
            float4 va = *(const float4*)(Arow + (size_t)row * EDIM + kc + 4 * gq);
            *(float4*)(As + row * CHUNK + sw) = va;
            float4 vb = *(const float4*)(Brow + (size_t)row * EDIM + kc + 4 * gq);
            *(float4*)(Bs + row * CHUNK + sw) = vb;
        }
        __syncthreads();
        int swa = ty & 7, swb = tx & 7;
        for (int g = 0; g < nq; ++g) {
            float4 a0 = *(const float4*)(As + (ty     ) * CHUNK + 4 * (g ^ swa));
            float4 a1 = *(const float4*)(As + (ty + 8 ) * CHUNK + 4 * (g ^ swa));
            float4 a2 = *(const float4*)(As + (ty + 16) * CHUNK + 4 * (g ^ swa));
            float4 a3 = *(const float4*)(As + (ty + 24) * CHUNK + 4 * (g ^ swa));
            float4 b0 = *(const float4*)(Bs + (tx     ) * CHUNK + 4 * (g ^ swb));
            float4 b1 = *(const float4*)(Bs + (tx + 16) * CHUNK + 4 * (g ^ swb));
            float4 av[4] = {a0, a1, a2, a3};
            float4 bv[2] = {b0, b1};
            #pragma unroll
            for (int i = 0; i < 4; i++)
                #pragma unroll
                for (int j = 0; j < 2; j++) {
                    acc[i][j] = fmaf(av[i].x, bv[j].x, acc[i][j]);
                    acc[i][j] = fmaf(av[i].y, bv[j].y, acc[i][j]);
                    acc[i][j] = fmaf(av[i].z, bv[j].z, acc[i][j]);
                    acc[i][j] = fmaf(av[i].w, bv[j].w, acc[i][j]);
                }
        }
        __syncthreads();
    }
    float* dst = dots + (size_t)blk * (N2 * N2);
    #pragma unroll
    for (int i = 0; i < 4; i++) {
        int row = ty + 8 * i;
        if (row < 31) {
            if (tx < 31)      dst[row * 31 + tx]      = acc[i][0];
            if (tx + 16 < 31) dst[row * 31 + tx + 16] = acc[i][1];
        }
    }
}

// ---------- per-site K=7 iterated softmax ----------
__global__ __launch_bounds__(256) void softmax_k(const float* __restrict__ dots,
                                                 const float* __restrict__ yn,
                                                 const float* __restrict__ tempv,
                                                 float* __restrict__ wkout) {
    __shared__ float sred[4];
    int site = blockIdx.x;
    int b = site / NSITE; int ij = site % NSITE;
    int i1 = ij / N2, i2 = ij % N2;
    int t = threadIdx.x;
    int b1 = min(max(i1 - 7, 0), 16);
    int b2 = min(max(i2 - 7, 0), 16);
    float logit = -1e9f;
    if (t < NOFF) {
        int dj = t / SWIN, dc = t % SWIN;
        int j1 = b1 + dj, j2 = b2 + dc;
        float dot = dots[((size_t)(b * N1 + i1) * SWIN + dj) * (N2 * N2) + i2 * 31 + j2];
        float xn = yn[(b * N1 + j1) * N2 + j2];
        float d = yn[site] + xn - 2.f * dot;
        logit = -d / tempv[site];
        if (j1 == i1 && j2 == i2) logit = -1e9f;
    }
    float* wkr = wkout + (size_t)site * (KK * NOFF);
    for (int k = 0; k < KK; k++) {
        float m = block_max(logit, sred);
        float ex = expf(logit - m);
        float s = block_sum(ex, sred);
        float wgt = ex / s;
        if (t < NOFF) wkr[k * NOFF + t] = wgt;
        logit += log1pf(-fminf(wgt, 1.f - 1e-6f));
    }
}

// ---------- ypT build: ypT[b][e][j1*32+j2] bf16, zero at j2==31 ----------
__global__ __launch_bounds__(256) void ypt_k(const float* __restrict__ xd,
                                             unsigned short* __restrict__ ypT) {
    int row = blockIdx.x;          // b*800 + e
    int b = row / 800, e = row % 800;
    int cd = e & 7, pp = e >> 3;
    int pi = pp / 10, pj = pp % 10;
    const float* src = xd + ((size_t)(b * 8 + cd) * HH + pi) * WW + pj;
    unsigned short* dst = ypT + (size_t)row * COLP;
    for (int it = 0; it < 4; ++it) {
        int col = it * 256 + threadIdx.x;
        if (col < COLP) {
            int j1 = col >> 5, j2 = col & 31;
            unsigned short v = 0;
            if (j2 < 31) v = f2bf(src[(j1 * 5) * WW + j2 * 5]);
            dst[col] = v;
        }
    }
}

// ---------- A build: A[b][i1][m=256][kc=480] bf16 from Wk (zero-padded) ----------
__global__ __launch_bounds__(256) void abuild_k(const float* __restrict__ wk,
                                                unsigned short* __restrict__ Aglob) {
    int idx = blockIdx.x * 256 + threadIdx.x;      // one u8v each
    if (idx >= 2 * 31 * 256 * 60) return;
    int kc8 = (idx % 60) * 8;
    int m   = (idx / 60) % 256;
    int i1  = (idx / (60 * 256)) % 31;
    int b   = idx / (60 * 256 * 31);
    int dj = kc8 >> 5, j2base = kc8 & 31;          // 8-run stays in one dj
    int pglob = m >> 4, slot = m & 15;
    int s = (slot >= 7) ? 1 : 0;
    int i2 = 2 * pglob + s;
    int k = slot - 7 * s;
    bool valid = (slot < 14) && (i2 <= 30);
    u8v o;
    #pragma unroll
    for (int u = 0; u < 8; ++u) o[u] = 0;
    if (valid) {
        int b2 = min(max(i2 - 7, 0), 16);
        int site = (b * N1 + i1) * N2 + i2;
        const float* wr = wk + (size_t)site * (KK * NOFF) + k * NOFF + dj * SWIN - b2;
        #pragma unroll
        for (int u = 0; u < 8; ++u) {
            int j2 = j2base + u;
            int dc = j2 - b2;
            if (j2 < 31 && dc >= 0 && dc < SWIN) o[u] = f2bf(wr[j2]);
        }
    }
    *(u8v*)(Aglob + (size_t)idx * 8) = o;
}

// ---------- agg GEMM: per (b,i1): C[256 m][800 e] = A[256x480] * ypT-slice^T ----------
// epilogue folds directly into acc via atomicAdd
__global__ __launch_bounds__(256) void agg_gemm_k(const unsigned short* __restrict__ Aglob,
                                                  const unsigned short* __restrict__ ypT,
                                                  float* __restrict__ acc) {
    __shared__ unsigned short As[128 * 40];   // 128 m-rows x (32+8) k
    __shared__ unsigned short Bs[160 * 40];   // 160 e-rows x (32+8) k
    int blk = blockIdx.x;                     // b*310 + i1*10 + mh*5 + nc
    int b = blk / 310; int r = blk % 310;
    int i1 = r / 10; int r2 = r % 10;
    int mh = r2 / 5, nc = r2 % 5;
    int b1 = min(max(i1 - 7, 0), 16);
    int t = threadIdx.x;
    int wv = t >> 6, lane = t & 63;
    int wm = (wv & 1) * 64, we = (wv >> 1) * 80;
    const unsigned short* Ab = Aglob + ((size_t)(b * N1 + i1) * 256 + mh * 128) * KP;
    const unsigned short* Bb = ypT + ((size_t)b * 800 + nc * 160) * COLP + b1 * 32;
    f4v accr[4][5];
    #pragma unroll
    for (int mt = 0; mt < 4; ++mt)
        #pragma unroll
        for (int et = 0; et < 5; ++et) { f4v z = {0.f,0.f,0.f,0.f}; accr[mt][et] = z; }
    for (int ks = 0; ks < 15; ++ks) {
        __syncthreads();
        #pragma unroll
        for (int it = 0; it < 2; ++it) {
            int idx = t + it * 256;
            int row = idx >> 2, seg = idx & 3;
            *(u8v*)(As + row * 40 + seg * 8) = *(const u8v*)(Ab + (size_t)row * KP + ks * 32 + seg * 8);
        }
        #pragma unroll
        for (int it = 0; it < 3; ++it) {
            int idx = t + it * 256;
            if (idx < 640) {
                int row = idx >> 2, seg = idx & 3;
                *(u8v*)(Bs + row * 40 + seg * 8) = *(const u8v*)(Bb + (size_t)row * COLP + ks * 32 + seg * 8);
            }
        }
        __syncthreads();
        s8v af[4], bf[5];
        #pragma unroll
        for (int mt = 0; mt < 4; ++mt)
            af[mt] = *(const s8v*)((const short*)As + (wm + mt * 16 + (lane & 15)) * 40 + (lane >> 4) * 8);
        #pragma unroll
        for (int et = 0; et < 5; ++et)
            bf[et] = *(const s8v*)((const short*)Bs + (we + et * 16 + (lane & 15)) * 40 + (lane >> 4) * 8);
        #pragma unroll
        for (int mt = 0; mt < 4; ++mt)
            #pragma unroll
            for (int et = 0; et < 5; ++et)
                accr[mt][et] = __builtin_amdgcn_mfma_f32_16x16x32_bf16(af[mt], bf[et], accr[mt][et], 0, 0, 0);
    }
    // epilogue: decode (m -> i2,k), (e -> pi,pj,cd), atomic fold into acc
    #pragma unroll
    for (int mt = 0; mt < 4; ++mt) {
        int mbase = mh * 128 + wm + mt * 16 + (lane >> 4) * 4;
        #pragma unroll
        for (int c = 0; c < 4; ++c) {
            int m = mbase + c;
            int pglob = m >> 4, slot = m & 15;
            if (slot >= 14) continue;
            int s = (slot >= 7) ? 1 : 0;
            int i2 = 2 * pglob + s;
            if (i2 > 30) continue;
            int k = slot - 7 * s;
            #pragma unroll
            for (int et = 0; et < 5; ++et) {
                int eg = nc * 160 + we + et * 16 + (lane & 15);
                int cd = eg & 7, pp = eg >> 3;
                int pi = pp / 10, pj = pp % 10;
                int h = i1 * STR + pi, w_ = i2 * STR + pj;
                int ch = (k + 1) * CDATA + cd;
                atomicAdd(acc + ((size_t)(b * 64 + ch) * HH + h) * WW + w_, accr[mt][et][c]);
            }
        }
    }
}

// ---------- finalize: out = [x_data ; acc/cnt - x_data] ----------
__global__ __launch_bounds__(256) void finalize_k(const float* __restrict__ acc,
                                                  const float* __restrict__ xd,
                                                  float* __restrict__ out) {
    int idx = blockIdx.x * 256 + threadIdx.x;
    if (idx >= BN * 64 * HH * WW) return;
    int w_ = idx % WW; int h = (idx / WW) % HH;
    int ch = (idx / (HH * WW)) % 64; int b = idx / (64 * HH * WW);
    int cd = ch & 7; int kk = ch >> 3;
    float xv = xd[((size_t)(b * CDATA + cd) * HH + h) * WW + w_];
    float o;
    if (kk == 0) {
        o = xv;
    } else {
        int lo1 = max(0, (h - 5) / 5),  hi1 = min(30, h / 5);
        int lo2 = max(0, (w_ - 5) / 5), hi2 = min(30, w_ / 5);
        float cnt = (float)((hi1 - lo1 + 1) * (hi2 - lo2 + 1));
        o = acc[idx] / cnt - xv;
    }
    out[idx] = o;
}

extern "C" void kernel_launch(void* const* d_in, const int* in_sizes, int n_in,
                              void* d_out, int out_size, void* d_ws, size_t ws_size,
                              hipStream_t stream) {
    (void)in_sizes; (void)n_in; (void)out_size; (void)ws_size;
    const float* x_data = (const float*)d_in[0];
    const float* x_faet = (const float*)d_in[1];
    const float* ew1 = (const float*)d_in[2];  const float* eb1 = (const float*)d_in[3];
    const float* ew2 = (const float*)d_in[4];  const float* eb2 = (const float*)d_in[5];
    const float* ew3 = (const float*)d_in[6];  const float* eb3 = (const float*)d_in[7];
    const float* tw1 = (const float*)d_in[8];  const float* tb1 = (const float*)d_in[9];
    const float* tw2 = (const float*)d_in[10]; const float* tb2 = (const float*)d_in[11];
    const float* tw3 = (const float*)d_in[12]; const float* tb3 = (const float*)d_in[13];
    float* out = (float*)d_out;

    // workspace layout (bytes), total 44.8 MB:
    // h1 [0, 13107200)                bf16 conv1 out -> fp32 Wk (alias, after conv2)
    // h2 [13107200, 26214400)         bf16 conv2 out -> dots (alias) -> fp32 acc (alias)
    // wp [26214400, 26361856)         conv2 packed weights
    // yn/tempv small
    // ypT [26378240, 29552640)        bf16 patch-transpose
    // xe  [29552640, 31191040)        -> overlaid by Aglob after use
    // ltm [31191040, 31395840)        -> overlaid
    // ye  [31395840, 37546240)        -> overlaid
    // Aglob [29552640, 44789760)      bf16 agg A matrices (built after softmax)
    char* base = (char*)d_ws;
    unsigned short* h1 = (unsigned short*)(base);
    unsigned short* h2 = (unsigned short*)(base + 13107200);
    unsigned short* wp = (unsigned short*)(base + 26214400);
    float* yn    = (float*)(base + 26361856);
    float* tempv = (float*)(base + 26370048);
    unsigned short* ypT = (unsigned short*)(base + 26378240);
    float* xe    = (float*)(base + 29552640);
    float* ltm   = (float*)(base + 31191040);
    float* ye    = (float*)(base + 31395840);
    unsigned short* Aglob = (unsigned short*)(base + 29552640);
    float* dots  = (float*)h2;
    float* wkbuf = (float*)h1;
    float* acc   = (float*)h2;

    prepack_w2_k<<<(2 * 64 * 576 + 255) / 256, 256, 0, stream>>>(ew2, tw2, wp);
    conv1_k<<<dim3(10, 10, 16), dim3(16, 16), 0, stream>>>(x_faet, ew1, eb1, tw1, tb1, h1);
    conv2_mfma_k<<<dim3(800, 2), 256, 0, stream>>>(h1, wp, eb2, tb2, h2);
    conv3_k<<<dim3(10, 10, 4), dim3(16, 16), 0, stream>>>(h2, ew3, eb3, tw3, tb3, xe, ltm);

    im2patch_k<<<BN * NSITE, 256, 0, stream>>>(xe, ltm, ye, yn, tempv);
    ypt_k<<<BN * 800, 256, 0, stream>>>(x_data, ypT);
    gram_k<<<BN * N1 * SWIN, 128, 0, stream>>>(ye, dots);
    softmax_k<<<BN * NSITE, 256, 0, stream>>>(dots, yn, tempv, wkbuf);

    abuild_k<<<(2 * 31 * 256 * 60) / 256, 256, 0, stream>>>(wkbuf, Aglob);
    hipMemsetAsync(acc, 0, 13107200, stream);
    agg_gemm_k<<<BN * 310, 256, 0, stream>>>(Aglob, ypT, acc);
    finalize_k<<<(BN * 64 * HH * WW) / 256, 256, 0, stream>>>(acc, x_data, out);
}

// Round 5
// 270.503 us; speedup vs baseline: 2.0257x; 2.0257x over previous
//
#include <hip/hip_runtime.h>
#include <math.h>

#define BN 2
#define HH 160
#define WW 160
#define CDATA 8
#define PS 10
#define STR 5
#define N1 31
#define N2 31
#define NSITE (N1*N2)
#define SWIN 15
#define NOFF 225
#define KK 7
#define EDIM 800
#define CHUNK 256
#define NPIX 25600          // HH*WW
#define LP 40               // conv2 LDS pitch (ushorts)
#define KP 480              // agg A k-pitch (= 15 dj * 32 j2-slots)
#define COLP 992            // ypT col pitch (31 j1 * 32 j2-slots)

typedef __attribute__((ext_vector_type(8))) short s8v;
typedef __attribute__((ext_vector_type(8))) unsigned short u8v;
typedef __attribute__((ext_vector_type(4))) float f4v;

__device__ __forceinline__ unsigned short f2bf(float f) {
    unsigned u = __float_as_uint(f);
    return (unsigned short)((u + 0x7FFFu + ((u >> 16) & 1u)) >> 16);
}
__device__ __forceinline__ float bf2f(unsigned short h) {
    return __uint_as_float(((unsigned)h) << 16);
}

// ---------- block reductions ----------
__device__ __forceinline__ float block_sum(float v, float* sred) {
    #pragma unroll
    for (int o = 32; o; o >>= 1) v += __shfl_xor(v, o);
    __syncthreads();
    if ((threadIdx.x & 63) == 0) sred[threadIdx.x >> 6] = v;
    __syncthreads();
    return sred[0] + sred[1] + sred[2] + sred[3];
}
__device__ __forceinline__ float block_max(float v, float* sred) {
    #pragma unroll
    for (int o = 32; o; o >>= 1) v = fmaxf(v, __shfl_xor(v, o));
    __syncthreads();
    if ((threadIdx.x & 63) == 0) sred[threadIdx.x >> 6] = v;
    __syncthreads();
    return fmaxf(fmaxf(sred[0], sred[1]), fmaxf(sred[2], sred[3]));
}

// ---------- prepack conv2 weights: [2][n=64][k=576] ----------
__global__ __launch_bounds__(256) void prepack_w2_k(const float* __restrict__ ew2,
                                                    const float* __restrict__ tw2,
                                                    unsigned short* __restrict__ wp) {
    int idx = blockIdx.x * 256 + threadIdx.x;
    if (idx >= 2 * 64 * 576) return;
    int which = idx / (64 * 576); int r = idx % (64 * 576);
    int n = r / 576, k = r % 576;
    int p = k / 64, c = k % 64;
    const float* w = which ? tw2 : ew2;
    wp[idx] = f2bf(w[(n * 64 + c) * 9 + p]);
}

// ---------- conv1 (e+t fused) -> bf16 NHWC h1 [b][pix][128] ----------
__global__ __launch_bounds__(256) void conv1_k(const float* __restrict__ xf,
                                               const float* __restrict__ ew1,
                                               const float* __restrict__ eb1,
                                               const float* __restrict__ tw1,
                                               const float* __restrict__ tb1,
                                               unsigned short* __restrict__ h1) {
    int x = blockIdx.x * 16 + threadIdx.x;
    int y = blockIdx.y * 16 + threadIdx.y;
    int z = blockIdx.z; int b = z >> 3, g = z & 7;
    const float* wgt  = (g < 4) ? ew1 : tw1;
    const float* bias = (g < 4) ? eb1 : tb1;
    int co0 = (g & 3) * 16;
    float acc[16];
    #pragma unroll
    for (int u = 0; u < 16; u++) acc[u] = bias[co0 + u];
    const float* inb = xf + (size_t)b * 8 * NPIX;
    for (int c = 0; c < 8; ++c) {
        const float* inc = inb + c * NPIX;
        #pragma unroll
        for (int dy = 0; dy < 3; ++dy) {
            int yy = y + dy - 1; bool yok = (yy >= 0 && yy < HH);
            #pragma unroll
            for (int dx = 0; dx < 3; ++dx) {
                int xx = x + dx - 1;
                float v = (yok && xx >= 0 && xx < WW) ? inc[yy * WW + xx] : 0.f;
                #pragma unroll
                for (int u = 0; u < 16; u++)
                    acc[u] = fmaf(v, wgt[((co0 + u) * 8 + c) * 9 + dy * 3 + dx], acc[u]);
            }
        }
    }
    u8v o0, o1;
    #pragma unroll
    for (int u = 0; u < 8; u++) o0[u] = f2bf(fmaxf(acc[u], 0.f));
    #pragma unroll
    for (int u = 0; u < 8; u++) o1[u] = f2bf(fmaxf(acc[8 + u], 0.f));
    unsigned short* dst = h1 + ((size_t)b * NPIX + y * WW + x) * 128 + g * 16;
    *(u8v*)dst = o0;
    *(u8v*)(dst + 8) = o1;
}

// ---------- conv2: bf16 MFMA implicit GEMM ----------
__global__ __launch_bounds__(256) void conv2_mfma_k(const unsigned short* __restrict__ h1,
                                                    const unsigned short* __restrict__ wp,
                                                    const float* __restrict__ eb2,
                                                    const float* __restrict__ tb2,
                                                    unsigned short* __restrict__ h2) {
    __shared__ unsigned short Al[64 * LP];
    __shared__ unsigned short Bl[64 * LP];
    const int t = threadIdx.x;
    const int which = blockIdx.y;
    const int m0 = blockIdx.x * 64;
    const int wv = t >> 6, lane = t & 63;
    const int n0w = (wv >> 1) * 32, m0w = (wv & 1) * 32;
    f4v a00 = {0.f,0.f,0.f,0.f}, a01 = a00, a10 = a00, a11 = a00;
    const unsigned short* wb = wp + (size_t)which * 64 * 576;
    const int sm = t >> 2, sq = (t & 3) * 8;
    const int mp = m0 + sm;
    const int b = mp / NPIX, rp = mp % NPIX;
    const int py = rp / WW, px = rp % WW;
    for (int step = 0; step < 18; ++step) {
        const int p = step >> 1, ch = (step & 1) * 32;
        const int dy = p / 3 - 1, dx = p % 3 - 1;
        s8v av = *(const s8v*)(wb + sm * 576 + p * 64 + ch + sq);
        s8v bv;
        #pragma unroll
        for (int j = 0; j < 8; j++) bv[j] = 0;
        int yy = py + dy, xx = px + dx;
        if (yy >= 0 && yy < HH && xx >= 0 && xx < WW)
            bv = *(const s8v*)((const short*)h1 + ((size_t)b * NPIX + yy * WW + xx) * 128 + which * 64 + ch + sq);
        __syncthreads();
        *(s8v*)((short*)Al + sm * LP + sq) = av;
        *(s8v*)((short*)Bl + sm * LP + sq) = bv;
        __syncthreads();
        s8v af0 = *(const s8v*)((const short*)Al + (n0w      + (lane & 15)) * LP + (lane >> 4) * 8);
        s8v af1 = *(const s8v*)((const short*)Al + (n0w + 16 + (lane & 15)) * LP + (lane >> 4) * 8);
        s8v bf0 = *(const s8v*)((const short*)Bl + (m0w      + (lane & 15)) * LP + (lane >> 4) * 8);
        s8v bf1 = *(const s8v*)((const short*)Bl + (m0w + 16 + (lane & 15)) * LP + (lane >> 4) * 8);
        a00 = __builtin_amdgcn_mfma_f32_16x16x32_bf16(af0, bf0, a00, 0, 0, 0);
        a01 = __builtin_amdgcn_mfma_f32_16x16x32_bf16(af0, bf1, a01, 0, 0, 0);
        a10 = __builtin_amdgcn_mfma_f32_16x16x32_bf16(af1, bf0, a10, 0, 0, 0);
        a11 = __builtin_amdgcn_mfma_f32_16x16x32_bf16(af1, bf1, a11, 0, 0, 0);
    }
    const float* bias = which ? tb2 : eb2;
    #pragma unroll
    for (int fj = 0; fj < 2; ++fj) {
        int nb = n0w + fj * 16 + (lane >> 4) * 4;
        f4v bv4 = *(const f4v*)(bias + nb);
        #pragma unroll
        for (int fi = 0; fi < 2; ++fi) {
            f4v ac = fj ? (fi ? a11 : a10) : (fi ? a01 : a00);
            int mm = m0 + m0w + fi * 16 + (lane & 15);
            ushort4 o;
            o.x = f2bf(fmaxf(ac[0] + bv4[0], 0.f));
            o.y = f2bf(fmaxf(ac[1] + bv4[1], 0.f));
            o.z = f2bf(fmaxf(ac[2] + bv4[2], 0.f));
            o.w = f2bf(fmaxf(ac[3] + bv4[3], 0.f));
            *(ushort4*)(h2 + ((size_t)which * 51200 + mm) * 64 + nb) = o;
        }
    }
}

// ---------- conv3 (e+t fused) ----------
__global__ __launch_bounds__(256) void conv3_k(const unsigned short* __restrict__ h2,
                                               const float* __restrict__ ew3,
                                               const float* __restrict__ eb3,
                                               const float* __restrict__ tw3,
                                               const float* __restrict__ tb3,
                                               float* __restrict__ xe,
                                               float* __restrict__ ltm) {
    int x = blockIdx.x * 16 + threadIdx.x;
    int y = blockIdx.y * 16 + threadIdx.y;
    int z = blockIdx.z; int b = z >> 1, which = z & 1;
    const unsigned short* h2b = h2 + ((size_t)which * 51200 + b * NPIX) * 64;
    if (which == 0) {
        float acc[8];
        #pragma unroll
        for (int u = 0; u < 8; u++) acc[u] = eb3[u];
        #pragma unroll
        for (int pos = 0; pos < 9; ++pos) {
            int yy = y + pos / 3 - 1, xx = x + pos % 3 - 1;
            if (yy < 0 || yy >= HH || xx < 0 || xx >= WW) continue;
            const unsigned short* row = h2b + ((size_t)yy * WW + xx) * 64;
            for (int cq = 0; cq < 8; ++cq) {
                u8v v = *(const u8v*)(row + cq * 8);
                #pragma unroll
                for (int j = 0; j < 8; ++j) {
                    float f = bf2f(v[j]);
                    int c = cq * 8 + j;
                    #pragma unroll
                    for (int u = 0; u < 8; u++)
                        acc[u] = fmaf(f, ew3[(u * 64 + c) * 9 + pos], acc[u]);
                }
            }
        }
        float* dst = xe + ((size_t)b * NPIX + y * WW + x) * 8;
        #pragma unroll
        for (int u = 0; u < 8; u++) dst[u] = acc[u];
    } else {
        float acc = tb3[0];
        #pragma unroll
        for (int pos = 0; pos < 9; ++pos) {
            int yy = y + pos / 3 - 1, xx = x + pos % 3 - 1;
            if (yy < 0 || yy >= HH || xx < 0 || xx >= WW) continue;
            const unsigned short* row = h2b + ((size_t)yy * WW + xx) * 64;
            for (int cq = 0; cq < 8; ++cq) {
                u8v v = *(const u8v*)(row + cq * 8);
                #pragma unroll
                for (int j = 0; j < 8; ++j)
                    acc = fmaf(bf2f(v[j]), tw3[(cq * 8 + j) * 9 + pos], acc);
            }
        }
        ltm[b * NPIX + y * WW + x] = acc;
    }
}

// ---------- im2patch (NHWC xe): ye[site][e] ----------
__global__ __launch_bounds__(256) void im2patch_k(const float* __restrict__ xe,
                                                  const float* __restrict__ ltm,
                                                  float* __restrict__ ye,
                                                  float* __restrict__ yn,
                                                  float* __restrict__ tempv) {
    __shared__ float sred[4];
    int site = blockIdx.x;
    int b = site / NSITE; int ij = site % NSITE;
    int i1 = ij / N2, i2 = ij % N2;
    int t = threadIdx.x;
    const float* xeb = xe + (size_t)b * NPIX * 8;
    float* yrow = ye + (size_t)site * EDIM;
    float ssq = 0.f;
    for (int e = t; e < EDIM; e += 256) {
        int rr = e / 80, rem = e % 80;
        float v = xeb[((size_t)(i1 * STR + rr) * WW + i2 * STR) * 8 + rem];
        yrow[e] = v; ssq += v * v;
    }
    float tot = block_sum(ssq, sred);
    if (t == 0) yn[site] = tot;
    float sl = 0.f;
    if (t < 100) {
        int rr = t / 10, q = t % 10;
        sl = ltm[(size_t)b * NPIX + (i1 * STR + rr) * WW + (i2 * STR + q)];
    }
    float slt = block_sum(sl, sred);
    if (t == 0) tempv[site] = expf(slt * (1.f / 100.f));
}

// ---------- gram: per (b, i1, dj) 31x31 dot block ----------
__global__ __launch_bounds__(128) void gram_k(const float* __restrict__ ye,
                                              float* __restrict__ dots) {
    __shared__ float As[32 * CHUNK];
    __shared__ float Bs[32 * CHUNK];
    int blk = blockIdx.x;
    int b = blk / 465; int r = blk % 465;
    int i1 = r / 15, dj = r % 15;
    int b1 = min(max(i1 - 7, 0), 16);
    int j1 = b1 + dj;
    const float* Arow = ye + (size_t)(b * N1 + i1) * N2 * EDIM;
    const float* Brow = ye + (size_t)(b * N1 + j1) * N2 * EDIM;
    int t = threadIdx.x;
    int tx = t & 15, ty = t >> 4;
    float acc[4][2];
    #pragma unroll
    for (int i = 0; i < 4; i++) { acc[i][0] = 0.f; acc[i][1] = 0.f; }
    for (int kc = 0; kc < EDIM; kc += CHUNK) {
        int len = min(CHUNK, EDIM - kc);
        int nq = len >> 2;
        for (int idx = t; idx < 31 * nq; idx += 128) {
            int row = idx / nq, gq = idx % nq;
            int sw = 4 * (gq ^ (row & 7));
            float4 va = *(const float4*)(Arow + (size_t)row * EDIM + kc + 4 * gq);
            *(float4*)(As + row * CHUNK + sw) = va;
            float4 vb = *(const float4*)(Brow + (size_t)row * EDIM + kc + 4 * gq);
            *(float4*)(Bs + row * CHUNK + sw) = vb;
        }
        __syncthreads();
        int swa = ty & 7, swb = tx & 7;
        for (int g = 0; g < nq; ++g) {
            float4 a0 = *(const float4*)(As + (ty     ) * CHUNK + 4 * (g ^ swa));
            float4 a1 = *(const float4*)(As + (ty + 8 ) * CHUNK + 4 * (g ^ swa));
            float4 a2 = *(const float4*)(As + (ty + 16) * CHUNK + 4 * (g ^ swa));
            float4 a3 = *(const float4*)(As + (ty + 24) * CHUNK + 4 * (g ^ swa));
            float4 b0 = *(const float4*)(Bs + (tx     ) * CHUNK + 4 * (g ^ swb));
            float4 b1 = *(const float4*)(Bs + (tx + 16) * CHUNK + 4 * (g ^ swb));
            float4 av[4] = {a0, a1, a2, a3};
            float4 bv[2] = {b0, b1};
            #pragma unroll
            for (int i = 0; i < 4; i++)
                #pragma unroll
                for (int j = 0; j < 2; j++) {
                    acc[i][j] = fmaf(av[i].x, bv[j].x, acc[i][j]);
                    acc[i][j] = fmaf(av[i].y, bv[j].y, acc[i][j]);
                    acc[i][j] = fmaf(av[i].z, bv[j].z, acc[i][j]);
                    acc[i][j] = fmaf(av[i].w, bv[j].w, acc[i][j]);
                }
        }
        __syncthreads();
    }
    float* dst = dots + (size_t)blk * (N2 * N2);
    #pragma unroll
    for (int i = 0; i < 4; i++) {
        int row = ty + 8 * i;
        if (row < 31) {
            if (tx < 31)      dst[row * 31 + tx]      = acc[i][0];
            if (tx + 16 < 31) dst[row * 31 + tx + 16] = acc[i][1];
        }
    }
}

// ---------- per-site K=7 iterated softmax ----------
__global__ __launch_bounds__(256) void softmax_k(const float* __restrict__ dots,
                                                 const float* __restrict__ yn,
                                                 const float* __restrict__ tempv,
                                                 float* __restrict__ wkout) {
    __shared__ float sred[4];
    int site = blockIdx.x;
    int b = site / NSITE; int ij = site % NSITE;
    int i1 = ij / N2, i2 = ij % N2;
    int t = threadIdx.x;
    int b1 = min(max(i1 - 7, 0), 16);
    int b2 = min(max(i2 - 7, 0), 16);
    float logit = -1e9f;
    if (t < NOFF) {
        int dj = t / SWIN, dc = t % SWIN;
        int j1 = b1 + dj, j2 = b2 + dc;
        float dot = dots[((size_t)(b * N1 + i1) * SWIN + dj) * (N2 * N2) + i2 * 31 + j2];
        float xn = yn[(b * N1 + j1) * N2 + j2];
        float d = yn[site] + xn - 2.f * dot;
        logit = -d / tempv[site];
        if (j1 == i1 && j2 == i2) logit = -1e9f;
    }
    float* wkr = wkout + (size_t)site * (KK * NOFF);
    for (int k = 0; k < KK; k++) {
        float m = block_max(logit, sred);
        float ex = expf(logit - m);
        float s = block_sum(ex, sred);
        float wgt = ex / s;
        if (t < NOFF) wkr[k * NOFF + t] = wgt;
        logit += log1pf(-fminf(wgt, 1.f - 1e-6f));
    }
}

// ---------- ypT build: ypT[b][e][j1*32+j2] bf16, zero at j2==31 ----------
__global__ __launch_bounds__(256) void ypt_k(const float* __restrict__ xd,
                                             unsigned short* __restrict__ ypT) {
    int row = blockIdx.x;          // b*800 + e
    int b = row / 800, e = row % 800;
    int cd = e & 7, pp = e >> 3;
    int pi = pp / 10, pj = pp % 10;
    const float* src = xd + ((size_t)(b * 8 + cd) * HH + pi) * WW + pj;
    unsigned short* dst = ypT + (size_t)row * COLP;
    for (int it = 0; it < 4; ++it) {
        int col = it * 256 + threadIdx.x;
        if (col < COLP) {
            int j1 = col >> 5, j2 = col & 31;
            unsigned short v = 0;
            if (j2 < 31) v = f2bf(src[(j1 * 5) * WW + j2 * 5]);
            dst[col] = v;
        }
    }
}

// ---------- A build: A[b][i1][m=256][kc=480] bf16 from Wk (zero-padded) ----------
__global__ __launch_bounds__(256) void abuild_k(const float* __restrict__ wk,
                                                unsigned short* __restrict__ Aglob) {
    int idx = blockIdx.x * 256 + threadIdx.x;      // one u8v each
    if (idx >= 2 * 31 * 256 * 60) return;
    int kc8 = (idx % 60) * 8;
    int m   = (idx / 60) % 256;
    int i1  = (idx / (60 * 256)) % 31;
    int b   = idx / (60 * 256 * 31);
    int dj = kc8 >> 5, j2base = kc8 & 31;
    int pglob = m >> 4, slot = m & 15;
    int s = (slot >= 7) ? 1 : 0;
    int i2 = 2 * pglob + s;
    int k = slot - 7 * s;
    bool valid = (slot < 14) && (i2 <= 30);
    u8v o;
    #pragma unroll
    for (int u = 0; u < 8; ++u) o[u] = 0;
    if (valid) {
        int b2 = min(max(i2 - 7, 0), 16);
        int site = (b * N1 + i1) * N2 + i2;
        const float* wr = wk + (size_t)site * (KK * NOFF) + k * NOFF + dj * SWIN - b2;
        #pragma unroll
        for (int u = 0; u < 8; ++u) {
            int j2 = j2base + u;
            int dc = j2 - b2;
            if (j2 < 31 && dc >= 0 && dc < SWIN) o[u] = f2bf(wr[j2]);
        }
    }
    *(u8v*)(Aglob + (size_t)idx * 8) = o;
}

// ---------- agg GEMM: per (b,i1): C[256 m][800 e] = A[256x480] * ypT-slice^T ----------
// epilogue: plain bf16 stores into zbuf[b][i1][m][e] (each element written once)
__global__ __launch_bounds__(256) void agg_gemm_k(const unsigned short* __restrict__ Aglob,
                                                  const unsigned short* __restrict__ ypT,
                                                  unsigned short* __restrict__ zbuf) {
    __shared__ unsigned short As[128 * 40];
    __shared__ unsigned short Bs[160 * 40];
    int blk = blockIdx.x;                     // b*310 + i1*10 + mh*5 + nc
    int b = blk / 310; int r = blk % 310;
    int i1 = r / 10; int r2 = r % 10;
    int mh = r2 / 5, nc = r2 % 5;
    int b1 = min(max(i1 - 7, 0), 16);
    int t = threadIdx.x;
    int wv = t >> 6, lane = t & 63;
    int wm = (wv & 1) * 64, we = (wv >> 1) * 80;
    const unsigned short* Ab = Aglob + ((size_t)(b * N1 + i1) * 256 + mh * 128) * KP;
    const unsigned short* Bb = ypT + ((size_t)b * 800 + nc * 160) * COLP + b1 * 32;
    f4v accr[4][5];
    #pragma unroll
    for (int mt = 0; mt < 4; ++mt)
        #pragma unroll
        for (int et = 0; et < 5; ++et) { f4v z = {0.f,0.f,0.f,0.f}; accr[mt][et] = z; }
    for (int ks = 0; ks < 15; ++ks) {
        __syncthreads();
        #pragma unroll
        for (int it = 0; it < 2; ++it) {
            int idx = t + it * 256;
            int row = idx >> 2, seg = idx & 3;
            *(u8v*)(As + row * 40 + seg * 8) = *(const u8v*)(Ab + (size_t)row * KP + ks * 32 + seg * 8);
        }
        #pragma unroll
        for (int it = 0; it < 3; ++it) {
            int idx = t + it * 256;
            if (idx < 640) {
                int row = idx >> 2, seg = idx & 3;
                *(u8v*)(Bs + row * 40 + seg * 8) = *(const u8v*)(Bb + (size_t)row * COLP + ks * 32 + seg * 8);
            }
        }
        __syncthreads();
        s8v af[4], bf[5];
        #pragma unroll
        for (int mt = 0; mt < 4; ++mt)
            af[mt] = *(const s8v*)((const short*)As + (wm + mt * 16 + (lane & 15)) * 40 + (lane >> 4) * 8);
        #pragma unroll
        for (int et = 0; et < 5; ++et)
            bf[et] = *(const s8v*)((const short*)Bs + (we + et * 16 + (lane & 15)) * 40 + (lane >> 4) * 8);
        #pragma unroll
        for (int mt = 0; mt < 4; ++mt)
            #pragma unroll
            for (int et = 0; et < 5; ++et)
                accr[mt][et] = __builtin_amdgcn_mfma_f32_16x16x32_bf16(af[mt], bf[et], accr[mt][et], 0, 0, 0);
    }
    unsigned short* zb = zbuf + ((size_t)(b * N1 + i1) * 256 + mh * 128) * 800 + nc * 160;
    #pragma unroll
    for (int mt = 0; mt < 4; ++mt) {
        int mrow = wm + mt * 16 + (lane >> 4) * 4;
        #pragma unroll
        for (int et = 0; et < 5; ++et) {
            int ecol = we + et * 16 + (lane & 15);
            #pragma unroll
            for (int c = 0; c < 4; ++c)
                zb[(size_t)(mrow + c) * 800 + ecol] = f2bf(accr[mt][et][c]);
        }
    }
}

// ---------- finalize: gather-fold from zbuf; out = [x_data ; sum/cnt - x_data] ----------
__global__ __launch_bounds__(256) void finalize_k(const unsigned short* __restrict__ zbuf,
                                                  const float* __restrict__ xd,
                                                  float* __restrict__ out) {
    int idx = blockIdx.x * 256 + threadIdx.x;
    if (idx >= BN * 64 * HH * WW) return;
    int w_ = idx % WW; int h = (idx / WW) % HH;
    int ch = (idx / (HH * WW)) % 64; int b = idx / (64 * HH * WW);
    int cd = ch & 7; int kk = ch >> 3;
    float xv = xd[((size_t)(b * CDATA + cd) * HH + h) * WW + w_];
    float o;
    if (kk == 0) {
        o = xv;
    } else {
        int k = kk - 1;
        int lo1 = max(0, (h - 5) / 5),  hi1 = min(30, h / 5);
        int lo2 = max(0, (w_ - 5) / 5), hi2 = min(30, w_ / 5);
        float s = 0.f;
        for (int i1 = lo1; i1 <= hi1; ++i1) {
            int pi = h - 5 * i1;
            for (int i2 = lo2; i2 <= hi2; ++i2) {
                int pj = w_ - 5 * i2;
                int m = 16 * (i2 >> 1) + k + 7 * (i2 & 1);
                int e = (pi * 10 + pj) * 8 + cd;
                s += bf2f(zbuf[((size_t)(b * N1 + i1) * 256 + m) * 800 + e]);
            }
        }
        float cnt = (float)((hi1 - lo1 + 1) * (hi2 - lo2 + 1));
        o = s / cnt - xv;
    }
    out[idx] = o;
}

extern "C" void kernel_launch(void* const* d_in, const int* in_sizes, int n_in,
                              void* d_out, int out_size, void* d_ws, size_t ws_size,
                              hipStream_t stream) {
    (void)in_sizes; (void)n_in; (void)out_size; (void)ws_size;
    const float* x_data = (const float*)d_in[0];
    const float* x_faet = (const float*)d_in[1];
    const float* ew1 = (const float*)d_in[2];  const float* eb1 = (const float*)d_in[3];
    const float* ew2 = (const float*)d_in[4];  const float* eb2 = (const float*)d_in[5];
    const float* ew3 = (const float*)d_in[6];  const float* eb3 = (const float*)d_in[7];
    const float* tw1 = (const float*)d_in[8];  const float* tb1 = (const float*)d_in[9];
    const float* tw2 = (const float*)d_in[10]; const float* tb2 = (const float*)d_in[11];
    const float* tw3 = (const float*)d_in[12]; const float* tb3 = (const float*)d_in[13];
    float* out = (float*)d_out;

    // workspace layout (bytes), total 44.8 MB:
    // [0, 26214400)        h1 (bf16 conv1) -> Wk fp32 (h1 alias) / h2 (bf16 conv2) -> dots
    //                      -> zbuf bf16 [2][31][256][800] = 25,395,200 B (after Wk+dots dead)
    // wp   [26214400, 26361856)
    // yn/tempv small
    // ypT  [26378240, 29552640)
    // xe   [29552640, 31191040) -> Aglob overlays after conv3/im2patch
    // ltm  [31191040, 31395840)
    // ye   [31395840, 37546240)
    // Aglob[29552640, 44789760)
    char* base = (char*)d_ws;
    unsigned short* h1 = (unsigned short*)(base);
    unsigned short* h2 = (unsigned short*)(base + 13107200);
    unsigned short* wp = (unsigned short*)(base + 26214400);
    float* yn    = (float*)(base + 26361856);
    float* tempv = (float*)(base + 26370048);
    unsigned short* ypT = (unsigned short*)(base + 26378240);
    float* xe    = (float*)(base + 29552640);
    float* ltm   = (float*)(base + 31191040);
    float* ye    = (float*)(base + 31395840);
    unsigned short* Aglob = (unsigned short*)(base + 29552640);
    float* dots  = (float*)h2;
    float* wkbuf = (float*)h1;
    unsigned short* zbuf = (unsigned short*)base;   // overlays h1+h2 after both dead

    prepack_w2_k<<<(2 * 64 * 576 + 255) / 256, 256, 0, stream>>>(ew2, tw2, wp);
    conv1_k<<<dim3(10, 10, 16), dim3(16, 16), 0, stream>>>(x_faet, ew1, eb1, tw1, tb1, h1);
    conv2_mfma_k<<<dim3(800, 2), 256, 0, stream>>>(h1, wp, eb2, tb2, h2);
    conv3_k<<<dim3(10, 10, 4), dim3(16, 16), 0, stream>>>(h2, ew3, eb3, tw3, tb3, xe, ltm);

    im2patch_k<<<BN * NSITE, 256, 0, stream>>>(xe, ltm, ye, yn, tempv);
    ypt_k<<<BN * 800, 256, 0, stream>>>(x_data, ypT);
    gram_k<<<BN * N1 * SWIN, 128, 0, stream>>>(ye, dots);
    softmax_k<<<BN * NSITE, 256, 0, stream>>>(dots, yn, tempv, wkbuf);

    abuild_k<<<(2 * 31 * 256 * 60) / 256, 256, 0, stream>>>(wkbuf, Aglob);
    agg_gemm_k<<<BN * 310, 256, 0, stream>>>(Aglob, ypT, zbuf);
    finalize_k<<<(BN * 64 * HH * WW) / 256, 256, 0, stream>>>(zbuf, x_data, out);
}